// Round 4
// baseline (82.837 us; speedup 1.0000x reference)
//
#include <hip/hip_runtime.h>
#include <math.h>

#define NB 8
#define NH 192
#define NW 192
#define NPTS 1000
#define TW 32
#define TH 12
#define NPIX (TW * TH)  // 384

constexpr float KDOWN = 8.0f;

// ws layout: float parts[768][8] = {sp, spp, spt, stt, mp, mt, pad, pad},
// bid = b*96 + tile (batch-major); then unsigned counter at float index 6144.
// parts written unconditionally by every block before the counter bump ->
// no init needed. Counter init relies on the harness 0xAA ws poison (or 0);
// a wrong base fails loudly (d_out stays poisoned), never silently.

__global__ __launch_bounds__(512) void fused(const float* __restrict__ dens,
                                             const float* __restrict__ points,
                                             float* __restrict__ parts,
                                             unsigned* __restrict__ cnt,
                                             float* __restrict__ out) {
  __shared__ float4 kept[8][128];   // per-wave private compacted points, 16 KB
  __shared__ float d2all[8][NPIX];  // per-wave pixel min, 12 KB
  __shared__ float wmin[8];
  __shared__ float sred[6][6];  // waves 0..5 carry epilogue stats
  __shared__ double dres[8][3];
  __shared__ int lastFlag;

  const int b = blockIdx.z;
  const int col0 = blockIdx.x * TW;
  const int row0 = blockIdx.y * TH;
  const float cx = (float)col0 * KDOWN + 128.0f;  // tile-center origin
  const float cy = (float)row0 * KDOWN + 48.0f;
  const int tid = threadIdx.x;
  const int lane = tid & 63;
  const int w = tid >> 6;  // wave 0..7

  // --- prefetch dens early (1 px/thread for tid<384) ---
  float pred0 = 0.0f;
  if (tid < NPIX)
    pred0 = dens[((size_t)b * NH + row0 + (tid >> 5)) * NW + col0 + (tid & 31)];

  // --- phase 0: each wave loads its 1/8 of points (2 candidates/lane) ---
  const float2* __restrict__ pb =
      reinterpret_cast<const float2*>(points) + (size_t)b * NPTS;
  const int j0 = w * 64 + lane;  // < 512 < NPTS always
  const int j1 = 512 + j0;       // valid iff < NPTS
  const bool v1 = (j1 < NPTS);
  float2 P0 = pb[j0];
  float2 P1 = v1 ? pb[j1] : make_float2(1.0e19f, 1.0e19f);
  const float p0x = P0.x - cx, p0y = P0.y - cy;
  const float p1x = P1.x - cx, p1y = P1.y - cy;
  const float q0 = __builtin_fmaf(p0x, p0x, p0y * p0y);
  const float q1 = __builtin_fmaf(p1x, p1x, p1y * p1y);

  float qmin = fminf(q0, v1 ? q1 : 3.0e38f);
#pragma unroll
  for (int off = 32; off > 0; off >>= 1)
    qmin = fminf(qmin, __shfl_down(qmin, off));
  if (lane == 0) wmin[w] = qmin;
  __syncthreads();  // barrier 1

  float M2 = wmin[0];
#pragma unroll
  for (int i = 1; i < 8; ++i) M2 = fminf(M2, wmin[i]);
  // exact prune: keep j iff dist(c,j) <= min_k dist(c,k) + 2*halfdiag (+1 pad)
  // halfdiag over pixel centers = sqrt(124^2+44^2) = 131.576
  const float thr = sqrtf(M2) + 2.0f * 131.58f + 1.0f;
  const float T = thr * thr;

  // --- phase 1: per-wave ballot compaction into private LDS segment ---
  const bool k0 = (q0 <= T);
  const bool k1 = v1 && (q1 <= T);
  const unsigned long long m0 = __ballot(k0);
  const unsigned long long m1 = __ballot(k1);
  // strictly-below mask; branch-free and correct for lane 63 (r2/r3 had an
  // off-by-one here that wrote lane 63's point one slot too high).
  const unsigned long long below = (1ull << lane) - 1ull;
  if (k0) kept[w][__popcll(m0 & below)] = make_float4(p0x, p0y, q0, 0.0f);
  if (k1)
    kept[w][__popcll(m0) + __popcll(m1 & below)] =
        make_float4(p1x, p1y, q1, 0.0f);
  const int M = __popcll(m0) + __popcll(m1);  // wave-uniform kept count

  // --- phase 2: this wave scans its own list over all 384 pixels ---
  const int c = lane & 31;
  const int half = lane >> 5;
  const float xt = (float)(col0 + c) * KDOWN + 4.0f - cx;
  const float mx = -2.0f * xt;
  float my[6], xy2[6], d2[6];
#pragma unroll
  for (int k = 0; k < 6; ++k) {
    float ytk = (float)(row0 + half * 6 + k) * KDOWN + 4.0f - cy;
    my[k] = -2.0f * ytk;
    xy2[k] = __builtin_fmaf(xt, xt, ytk * ytk);
    d2[k] = 3.0e38f;
  }
  // wave-private LDS segment: order this wave's ds_writes before its ds_reads
  __builtin_amdgcn_wave_barrier();
  asm volatile("s_waitcnt lgkmcnt(0)" ::: "memory");

  if (M > 0) {
    for (int i0 = 0; i0 < M; i0 += 4) {
      int i1 = (i0 + 1 < M) ? i0 + 1 : M - 1;
      int i2 = (i0 + 2 < M) ? i0 + 2 : M - 1;
      int i3 = (i0 + 3 < M) ? i0 + 3 : M - 1;
      float4 A0 = kept[w][i0], A1 = kept[w][i1], A2 = kept[w][i2],
             A3 = kept[w][i3];
#pragma unroll
      for (int k = 0; k < 6; ++k) {
        float t0 = __builtin_fmaf(mx, A0.x, __builtin_fmaf(my[k], A0.y, A0.z));
        float t1 = __builtin_fmaf(mx, A1.x, __builtin_fmaf(my[k], A1.y, A1.z));
        float t2 = __builtin_fmaf(mx, A2.x, __builtin_fmaf(my[k], A2.y, A2.z));
        float t3 = __builtin_fmaf(mx, A3.x, __builtin_fmaf(my[k], A3.y, A3.z));
        d2[k] = fminf(d2[k], fminf(fminf(t0, t1), fminf(t2, t3)));
      }
    }
  }
#pragma unroll
  for (int k = 0; k < 6; ++k)
    d2all[w][(half * 6 + k) * TW + c] = d2[k] + xy2[k];
  __syncthreads();  // barrier 2

  // --- phase 3: epilogue, 1 px/thread for tid<384, 8-way min across waves ---
  float sp = 0.f, spp = 0.f, spt = 0.f, stt = 0.f, mp = 0.f, mt = 0.f;
  if (tid < NPIX) {
    float m8 = d2all[0][tid];
#pragma unroll
    for (int i = 1; i < 8; ++i) m8 = fminf(m8, d2all[i][tid]);
    float md = sqrtf(fmaxf(m8, 0.0f));
    float x = (8.0f - md) * 0.25f;
    float tg = 1.0f / (1.0f + __expf(-x));  // sigmoid((R-md)/(R/2))
    sp = pred0;
    spp = pred0 * pred0;
    spt = pred0 * tg;
    stt = tg * tg;
    mp = pred0;
    mt = tg;
  }
#pragma unroll
  for (int off = 32; off > 0; off >>= 1) {
    sp += __shfl_down(sp, off);
    spp += __shfl_down(spp, off);
    spt += __shfl_down(spt, off);
    stt += __shfl_down(stt, off);
    mp = fmaxf(mp, __shfl_down(mp, off));
    mt = fmaxf(mt, __shfl_down(mt, off));
  }
  if (lane == 0 && w < 6) {
    sred[w][0] = sp; sred[w][1] = spp; sred[w][2] = spt;
    sred[w][3] = stt; sred[w][4] = mp; sred[w][5] = mt;
  }
  __syncthreads();  // barrier 3

  // --- partial write: threads 0..5 combine + agent-scope store (L2-bypass,
  // visible cross-XCD; per-XCD L2s are NOT coherent for plain stores) ---
  const int bid = b * 96 + blockIdx.y * 6 + blockIdx.x;
  if (tid < 6) {
    float v;
    if (tid < 4)
      v = ((sred[0][tid] + sred[1][tid]) + (sred[2][tid] + sred[3][tid])) +
          (sred[4][tid] + sred[5][tid]);
    else
      v = fmaxf(fmaxf(fmaxf(sred[0][tid], sred[1][tid]),
                      fmaxf(sred[2][tid], sred[3][tid])),
                fmaxf(sred[4][tid], sred[5][tid]));
    __hip_atomic_store(parts + (size_t)bid * 8 + tid, v, __ATOMIC_RELAXED,
                       __HIP_MEMORY_SCOPE_AGENT);
  }
  __syncthreads();  // barrier 4: partial stores happen-before the bump

  if (tid == 0) {
    __threadfence();  // release: all 6 stores visible before counter bump
    unsigned old = __hip_atomic_fetch_add(cnt, 1u, __ATOMIC_ACQ_REL,
                                          __HIP_MEMORY_SCOPE_AGENT);
    // base is 0xAAAAAAAA (harness poison) or 0 (fresh zero); the two checks
    // can never both match within one pass.
    lastFlag = (old == 767u) || (old == 0xAAAAAAAAu + 767u);
  }
  __syncthreads();  // barrier 5: block-uniform flag

  if (lastFlag) {
    // --- last arriving block finalizes: wave w = batch w, lanes scan tiles ---
    double fsp = 0, fspp = 0, fspt = 0, fstt = 0;
    float fmp = 0.f, fmt = 0.f;
    for (int e = lane; e < 96; e += 64) {
      const float* src = parts + (size_t)(w * 96 + e) * 8;
      fsp += (double)__hip_atomic_load(src + 0, __ATOMIC_RELAXED,
                                       __HIP_MEMORY_SCOPE_AGENT);
      fspp += (double)__hip_atomic_load(src + 1, __ATOMIC_RELAXED,
                                        __HIP_MEMORY_SCOPE_AGENT);
      fspt += (double)__hip_atomic_load(src + 2, __ATOMIC_RELAXED,
                                        __HIP_MEMORY_SCOPE_AGENT);
      fstt += (double)__hip_atomic_load(src + 3, __ATOMIC_RELAXED,
                                        __HIP_MEMORY_SCOPE_AGENT);
      fmp = fmaxf(fmp, __hip_atomic_load(src + 4, __ATOMIC_RELAXED,
                                         __HIP_MEMORY_SCOPE_AGENT));
      fmt = fmaxf(fmt, __hip_atomic_load(src + 5, __ATOMIC_RELAXED,
                                         __HIP_MEMORY_SCOPE_AGENT));
    }
#pragma unroll
    for (int off = 32; off > 0; off >>= 1) {
      fsp += __shfl_down(fsp, off);
      fspp += __shfl_down(fspp, off);
      fspt += __shfl_down(fspt, off);
      fstt += __shfl_down(fstt, off);
      fmp = fmaxf(fmp, __shfl_down(fmp, off));
      fmt = fmaxf(fmt, __shfl_down(fmt, off));
    }
    if (lane == 0) {
      double cl = fabs(fsp / 64.0 - 1000.0);  // cell_area = 64, gt = 1000
      double pm = fmax((double)fmp, 1e-8);
      double tm = fmax((double)fmt, 1e-8);
      double mse = (fspp / (pm * pm) - 2.0 * fspt / (pm * tm) +
                    fstt / (tm * tm)) /
                   36864.0;
      dres[w][0] = cl;
      dres[w][1] = cl / 1000.0;
      dres[w][2] = (fmp > 1e-8f && fmt > 1e-8f) ? mse : 0.0;
    }
    __syncthreads();  // uniform: whole block is inside lastFlag
    if (tid == 0) {
      double cls = 0, sls = 0, sps = 0;
      for (int bb = 0; bb < 8; ++bb) {
        cls += dres[bb][0];
        sls += dres[bb][1];
        sps += dres[bb][2];
      }
      out[0] =
          (float)(2.0 * (cls / 8.0) + 0.5 * (sls / 8.0) + 0.1 * (sps / 8.0));
    }
  }
}

extern "C" void kernel_launch(void* const* d_in, const int* in_sizes, int n_in,
                              void* d_out, int out_size, void* d_ws,
                              size_t ws_size, hipStream_t stream) {
  const float* dens = (const float*)d_in[0];    // (B,1,H,W) f32
  const float* points = (const float*)d_in[1];  // (B,N,2)  f32
  float* parts = (float*)d_ws;                  // 768*8 floats
  unsigned* cnt = (unsigned*)((char*)d_ws + 768 * 8 * sizeof(float));
  float* out = (float*)d_out;

  dim3 grid(NW / TW, NH / TH, NB);  // (6,16,8) = 768 blocks, 8 waves each
  hipLaunchKernelGGL(fused, grid, dim3(512), 0, stream, dens, points, parts,
                     cnt, out);
}

// Round 5
// 65.109 us; speedup vs baseline: 1.2723x; 1.2723x over previous
//
#include <hip/hip_runtime.h>
#include <math.h>

#define NB 8
#define NH 192
#define NW 192
#define NPTS 1000
#define TW 32
#define TH 12
#define NPIX (TW * TH)  // 384

constexpr float KDOWN = 8.0f;

// ws layout: float parts[768][8] = {sp, spp, spt, stt, mp, mt, pad, pad},
// bid = b*96 + tile (batch-major). Written unconditionally by every block ->
// no init kernel, no atomics; cross-kernel visibility via kernel boundary.
// (r4 lesson: per-block agent-scope release fences = buffer_wbl2 x768, -19us.)

__global__ __launch_bounds__(512) void heavy(const float* __restrict__ dens,
                                             const float* __restrict__ points,
                                             float* __restrict__ parts) {
  __shared__ float4 kept[8][128];   // per-wave private compacted points, 16 KB
  __shared__ float d2all[8][NPIX];  // per-wave pixel min, 12 KB
  __shared__ float sred[6][6];      // waves 0..5 carry epilogue stats

  const int b = blockIdx.z;
  const int col0 = blockIdx.x * TW;
  const int row0 = blockIdx.y * TH;
  const float cx = (float)col0 * KDOWN + 128.0f;  // tile-center origin
  const float cy = (float)row0 * KDOWN + 48.0f;
  const int tid = threadIdx.x;
  const int lane = tid & 63;
  const int w = tid >> 6;  // wave 0..7

  // --- prefetch dens early (1 px/thread for tid<384) ---
  float pred0 = 0.0f;
  if (tid < NPIX)
    pred0 = dens[((size_t)b * NH + row0 + (tid >> 5)) * NW + col0 + (tid & 31)];

  // --- phase 0: each wave loads its 1/8 of points (2 candidates/lane) ---
  const float2* __restrict__ pb =
      reinterpret_cast<const float2*>(points) + (size_t)b * NPTS;
  const int j0 = w * 64 + lane;  // < 512 < NPTS always
  const int j1 = 512 + j0;       // valid iff < NPTS
  const bool v1 = (j1 < NPTS);
  float2 P0 = pb[j0];
  float2 P1 = v1 ? pb[j1] : make_float2(1.0e19f, 1.0e19f);
  const float p0x = P0.x - cx, p0y = P0.y - cy;
  const float p1x = P1.x - cx, p1y = P1.y - cy;
  const float q0 = __builtin_fmaf(p0x, p0x, p0y * p0y);
  const float q1 = __builtin_fmaf(p1x, p1x, p1y * p1y);

  // wave-LOCAL min center-distance (no block-wide min, no barrier needed).
  // Exactness: for pixel p, global nearest n in wave w*'s subset, m* = that
  // wave's argmin: dist(c,n) <= dist(p,n)+h <= dist(p,m*)+h <= dist(c,m*)+2h.
  // So keeping dist(c,j) <= sqrt(qmin_w) + 2h (+1 pad) retains every pixel's
  // true argmin. h = max pixel-center offset = sqrt(124^2+44^2) = 131.576.
  float qmin = fminf(q0, v1 ? q1 : 3.0e38f);
#pragma unroll
  for (int off = 32; off > 0; off >>= 1)
    qmin = fminf(qmin, __shfl_down(qmin, off));
  qmin = __shfl(qmin, 0);
  const float thr = sqrtf(qmin) + 2.0f * 131.58f + 1.0f;
  const float T = thr * thr;

  // --- phase 1: per-wave ballot compaction into private LDS segment ---
  const bool k0 = (q0 <= T);
  const bool k1 = v1 && (q1 <= T);
  const unsigned long long m0 = __ballot(k0);
  const unsigned long long m1 = __ballot(k1);
  // strictly-below mask, branch-free, correct for lane 63 (r2/r3 bug fixed)
  const unsigned long long below = (1ull << lane) - 1ull;
  if (k0) kept[w][__popcll(m0 & below)] = make_float4(p0x, p0y, q0, 0.0f);
  if (k1)
    kept[w][__popcll(m0) + __popcll(m1 & below)] =
        make_float4(p1x, p1y, q1, 0.0f);
  const int M = __popcll(m0) + __popcll(m1);  // wave-uniform kept count, >= 1

  // --- phase 2: this wave scans its own list over all 384 pixels ---
  const int c = lane & 31;
  const int half = lane >> 5;
  const float xt = (float)(col0 + c) * KDOWN + 4.0f - cx;
  const float mx = -2.0f * xt;
  float my[6], xy2[6], d2[6];
#pragma unroll
  for (int k = 0; k < 6; ++k) {
    float ytk = (float)(row0 + half * 6 + k) * KDOWN + 4.0f - cy;
    my[k] = -2.0f * ytk;
    xy2[k] = __builtin_fmaf(xt, xt, ytk * ytk);
    d2[k] = 3.0e38f;
  }
  // wave-private LDS segment: order this wave's ds_writes before its ds_reads
  __builtin_amdgcn_wave_barrier();
  asm volatile("s_waitcnt lgkmcnt(0)" ::: "memory");

  for (int i0 = 0; i0 < M; i0 += 4) {
    int i1 = (i0 + 1 < M) ? i0 + 1 : M - 1;
    int i2 = (i0 + 2 < M) ? i0 + 2 : M - 1;
    int i3 = (i0 + 3 < M) ? i0 + 3 : M - 1;
    float4 A0 = kept[w][i0], A1 = kept[w][i1], A2 = kept[w][i2],
           A3 = kept[w][i3];
#pragma unroll
    for (int k = 0; k < 6; ++k) {
      float t0 = __builtin_fmaf(mx, A0.x, __builtin_fmaf(my[k], A0.y, A0.z));
      float t1 = __builtin_fmaf(mx, A1.x, __builtin_fmaf(my[k], A1.y, A1.z));
      float t2 = __builtin_fmaf(mx, A2.x, __builtin_fmaf(my[k], A2.y, A2.z));
      float t3 = __builtin_fmaf(mx, A3.x, __builtin_fmaf(my[k], A3.y, A3.z));
      d2[k] = fminf(d2[k], fminf(fminf(t0, t1), fminf(t2, t3)));
    }
  }
#pragma unroll
  for (int k = 0; k < 6; ++k)
    d2all[w][(half * 6 + k) * TW + c] = d2[k] + xy2[k];
  __syncthreads();  // barrier 1

  // --- phase 3: epilogue, 1 px/thread for tid<384, 8-way min across waves ---
  float sp = 0.f, spp = 0.f, spt = 0.f, stt = 0.f, mp = 0.f, mt = 0.f;
  if (tid < NPIX) {
    float m8 = d2all[0][tid];
#pragma unroll
    for (int i = 1; i < 8; ++i) m8 = fminf(m8, d2all[i][tid]);
    float md = sqrtf(fmaxf(m8, 0.0f));
    float x = (8.0f - md) * 0.25f;
    float tg = 1.0f / (1.0f + __expf(-x));  // sigmoid((R-md)/(R/2))
    sp = pred0;
    spp = pred0 * pred0;
    spt = pred0 * tg;
    stt = tg * tg;
    mp = pred0;
    mt = tg;
  }
#pragma unroll
  for (int off = 32; off > 0; off >>= 1) {
    sp += __shfl_down(sp, off);
    spp += __shfl_down(spp, off);
    spt += __shfl_down(spt, off);
    stt += __shfl_down(stt, off);
    mp = fmaxf(mp, __shfl_down(mp, off));
    mt = fmaxf(mt, __shfl_down(mt, off));
  }
  if (lane == 0 && w < 6) {
    sred[w][0] = sp; sred[w][1] = spp; sred[w][2] = spt;
    sred[w][3] = stt; sred[w][4] = mp; sred[w][5] = mt;
  }
  __syncthreads();  // barrier 2

  if (tid < 6) {
    float v;
    if (tid < 4)
      v = ((sred[0][tid] + sred[1][tid]) + (sred[2][tid] + sred[3][tid])) +
          (sred[4][tid] + sred[5][tid]);
    else
      v = fmaxf(fmaxf(fmaxf(sred[0][tid], sred[1][tid]),
                      fmaxf(sred[2][tid], sred[3][tid])),
                fmaxf(sred[4][tid], sred[5][tid]));
    const int bid = b * 96 + blockIdx.y * 6 + blockIdx.x;
    parts[(size_t)bid * 8 + tid] = v;  // plain store; kernel boundary = fence
  }
}

__global__ __launch_bounds__(512) void finalize(const float* __restrict__ parts,
                                                float* __restrict__ out) {
  __shared__ double dres[8][3];
  const int tid = threadIdx.x;
  const int w = tid >> 6;  // = batch
  const int lane = tid & 63;

  double sp = 0, spp = 0, spt = 0, stt = 0;
  float mp = 0.f, mt = 0.f;
  for (int e = lane; e < 96; e += 64) {
    const float* src = parts + (size_t)(w * 96 + e) * 8;
    sp += (double)src[0];
    spp += (double)src[1];
    spt += (double)src[2];
    stt += (double)src[3];
    mp = fmaxf(mp, src[4]);
    mt = fmaxf(mt, src[5]);
  }
#pragma unroll
  for (int off = 32; off > 0; off >>= 1) {
    sp += __shfl_down(sp, off);
    spp += __shfl_down(spp, off);
    spt += __shfl_down(spt, off);
    stt += __shfl_down(stt, off);
    mp = fmaxf(mp, __shfl_down(mp, off));
    mt = fmaxf(mt, __shfl_down(mt, off));
  }
  if (lane == 0) {
    double cl = fabs(sp / 64.0 - 1000.0);  // cell_area = 64, gt = 1000
    double pm = fmax((double)mp, 1e-8);
    double tm = fmax((double)mt, 1e-8);
    double mse =
        (spp / (pm * pm) - 2.0 * spt / (pm * tm) + stt / (tm * tm)) / 36864.0;
    dres[w][0] = cl;
    dres[w][1] = cl / 1000.0;
    dres[w][2] = (mp > 1e-8f && mt > 1e-8f) ? mse : 0.0;
  }
  __syncthreads();
  if (tid == 0) {
    double cls = 0, sls = 0, sps = 0;
    for (int bb = 0; bb < 8; ++bb) {
      cls += dres[bb][0];
      sls += dres[bb][1];
      sps += dres[bb][2];
    }
    out[0] = (float)(2.0 * (cls / 8.0) + 0.5 * (sls / 8.0) + 0.1 * (sps / 8.0));
  }
}

extern "C" void kernel_launch(void* const* d_in, const int* in_sizes, int n_in,
                              void* d_out, int out_size, void* d_ws,
                              size_t ws_size, hipStream_t stream) {
  const float* dens = (const float*)d_in[0];    // (B,1,H,W) f32
  const float* points = (const float*)d_in[1];  // (B,N,2)  f32
  float* parts = (float*)d_ws;                  // 768*8 floats
  float* out = (float*)d_out;

  dim3 grid(NW / TW, NH / TH, NB);  // (6,16,8) = 768 blocks, 8 waves each
  hipLaunchKernelGGL(heavy, grid, dim3(512), 0, stream, dens, points, parts);
  hipLaunchKernelGGL(finalize, dim3(1), dim3(512), 0, stream, parts, out);
}